// Round 9
// baseline (360.666 us; speedup 1.0000x reference)
//
#include <hip/hip_runtime.h>

// Problem constants (fixed by setup_inputs)
#define NNODES 50000
#define NEDGES 800000
#define DIM    128
#define NRELS  4               // edge relations; weight slice 4 = self-loop
#define NB     (NRELS*NNODES)  // 200000 (rel,dst) bins
#define NBLKS  98              // scan chunks: 98*2048 = 200704 >= NB+1

typedef __attribute__((ext_vector_type(8))) short bf16x8;
typedef __attribute__((ext_vector_type(8))) unsigned short u16x8;
typedef __attribute__((ext_vector_type(4))) float f32x4;

// ---- ws layout (bytes) ----
#define SSRC_OFF   0            // u32[NEDGES+16]        3,200,064
#define CNT_OFF    3200256      // u32[200704]             802,816 (bins -> excl scan)
#define BSUM_OFF   4003072      // u32[128]
#define CTRL_OFF   4003584      // u32[64]: [8..12] tile offsets per rel
#define LHIST_OFF  4003840      // u32[256] (rel,lenb) histogram
#define LBASE_OFF  4004864      // u32[256] slot base per (rel,lenb) bin
#define GCUR_OFF   4005888      // u32[256] running cursor per bin
#define SSTART_OFF 4006912      // u32[NSLOTS]             800,512
#define SLEN_OFF   4807424      // u32[NSLOTS]             800,512
#define CUR_OFF    5607936      // u32[NB]                 800,256
#define SLOTOF_OFF 6408192      // u32[NB] (0xFFFFFFFF = empty)  800,256
#define WT_OFF     7208448      // bf16[5*128*128]         163,840
#define XBF_OFF    7372288      // bf16[NNODES*DIM]     12,800,000
#define GMAX_OFF   20172288     // bf16[NSLOTS*128]     51,232,768 -> total ~71.4 MB
#define NZ2        ((SLOTOF_OFF - BSUM_OFF) / 4)  // 601,280 u32 zeroed in k_prep

__device__ __forceinline__ unsigned short f2bf(float f) {  // RNE f32->bf16
  unsigned u = __float_as_uint(f);
  return (unsigned short)((u + 0x7FFFu + ((u >> 16) & 1u)) >> 16);
}
__device__ __forceinline__ float bf2f(unsigned short u) {
  return __uint_as_float(((unsigned)u) << 16);
}

// ---- prep: x f32->bf16, W transpose+convert, zero scan metadata, slotof=-1,
//      AND (rel,dst) histogram (cnt was zeroed by the preceding hipMemsetAsync) ----
__global__ void k_prep(const float* __restrict__ x, unsigned short* __restrict__ xbf,
                       const float* __restrict__ W, unsigned short* __restrict__ Wt,
                       const int* __restrict__ rel, const int* __restrict__ dst,
                       unsigned* __restrict__ cnt, unsigned* __restrict__ z2,
                       unsigned* __restrict__ sf) {
  int i = blockIdx.x * blockDim.x + threadIdx.x;
  if (i < NNODES * DIM / 8) {
    const float4* p = (const float4*)x + i * 2;
    float4 v0 = p[0], v1 = p[1];
    u16x8 o;
    o[0] = f2bf(v0.x); o[1] = f2bf(v0.y); o[2] = f2bf(v0.z); o[3] = f2bf(v0.w);
    o[4] = f2bf(v1.x); o[5] = f2bf(v1.y); o[6] = f2bf(v1.z); o[7] = f2bf(v1.w);
    *(u16x8*)(xbf + i * 8) = o;
  }
  if (i < 5 * DIM * DIM) {
    int r = i >> 14, rem = i & 16383, k = rem >> 7, c = rem & 127;
    Wt[(r << 14) + (c << 7) + k] = f2bf(W[i]);
  }
  if (i < NZ2) z2[i] = 0u;
  if (i < NB) sf[i] = 0xFFFFFFFFu;
  if (i < NEDGES) {
    int r = rel[i]; r = r < 0 ? 0 : (r > NRELS - 1 ? NRELS - 1 : r);
    atomicAdd(&cnt[r * NNODES + dst[i]], 1u);
  }
}

// ---- block-local exclusive scan of 2048-chunks, in place + fused (rel,len) histogram ----
__global__ void k_scanA(unsigned* __restrict__ cnt, unsigned* __restrict__ bsum,
                        unsigned* __restrict__ lhist) {
  __shared__ unsigned sh[256];
  __shared__ unsigned sh2[256];
  int tid = threadIdx.x;
  int base = blockIdx.x * 2048 + tid * 8;
  unsigned v[8], tsum = 0;
#pragma unroll
  for (int j = 0; j < 8; j++) { v[j] = cnt[base + j]; tsum += v[j]; }
  sh2[tid] = 0u;
  __syncthreads();
#pragma unroll
  for (int j = 0; j < 8; j++) {
    int b = base + j;
    if (v[j] && b < NB) {
      int r = b / NNODES;
      atomicAdd(&sh2[(r << 6) + (int)min(v[j], 63u)], 1u);
    }
  }
  sh[tid] = tsum;
  __syncthreads();
  for (int off = 1; off < 256; off <<= 1) {
    unsigned t = (tid >= off) ? sh[tid - off] : 0u;
    __syncthreads();
    sh[tid] += t;
    __syncthreads();
  }
  unsigned run = sh[tid] - tsum;
#pragma unroll
  for (int j = 0; j < 8; j++) { unsigned t = v[j]; cnt[base + j] = run; run += t; }
  if (tid == 255) bsum[blockIdx.x] = sh[255];
  if (sh2[tid]) atomicAdd(&lhist[tid], sh2[tid]);
}

// ---- fused: blocks 0..NBLKS-1 add block-prefix to chunks; block NBLKS does lscan ----
__global__ void k_fix(unsigned* __restrict__ cnt, const unsigned* __restrict__ bsum,
                      const unsigned* __restrict__ lhist, unsigned* __restrict__ lbase,
                      unsigned* __restrict__ ctrl) {
  int blk = blockIdx.x;
  int tid = threadIdx.x;
  if (blk < NBLKS) {
    if (blk == 0) return;
    unsigned p = 0;
    for (int k = 0; k < blk; k++) p += bsum[k];
    int base = blk * 2048 + tid * 8;
#pragma unroll
    for (int j = 0; j < 8; j++) cnt[base + j] += p;
    return;
  }
  // lscan: scan of 256 (rel,lenb) bins -> per-bin slot base + per-rel tile offsets.
  __shared__ unsigned sh[256];
  __shared__ unsigned pbs[NRELS], rex[NRELS];
  unsigned v = lhist[tid];
  sh[tid] = v;
  __syncthreads();
  for (int off = 1; off < 256; off <<= 1) {
    unsigned t = (tid >= off) ? sh[tid - off] : 0u;
    __syncthreads();
    sh[tid] += t;
    __syncthreads();
  }
  unsigned ex = sh[tid] - v;  // exclusive prefix
  if (tid == 0) {
    unsigned tt = 0;
    ctrl[8] = 0;
    for (int r = 0; r < NRELS; r++) {
      unsigned hi = sh[r * 64 + 63];
      unsigned lo = (r == 0) ? 0u : sh[r * 64 - 1];
      rex[r] = lo;
      pbs[r] = tt * 16u;            // slot base of rel region (16-aligned)
      tt += (hi - lo + 15u) / 16u;  // tiles for this rel
      ctrl[9 + r] = tt;
    }
  }
  __syncthreads();
  lbase[tid] = pbs[tid >> 6] + (ex - rex[tid >> 6]);
}

// ---- fused: blocks 0..781 gfill (LDS-ranked slots); blocks 782.. scat src values ----
__global__ void k_fill(const int* __restrict__ rel, const int* __restrict__ dst,
                       const int* __restrict__ src, const unsigned* __restrict__ cnt,
                       const unsigned* __restrict__ lbase, unsigned* __restrict__ gcur,
                       unsigned* __restrict__ sstart, unsigned* __restrict__ slen,
                       unsigned* __restrict__ slotof, unsigned* __restrict__ cur,
                       unsigned* __restrict__ ssrc) {
  int tid = threadIdx.x;
  if (blockIdx.x < 782) {
    __shared__ unsigned h[256], basearr[256];
    h[tid] = 0u;
    __syncthreads();
    int b = blockIdx.x * 256 + tid;
    unsigned start = 0, len = 0, loc = 0;
    int bin = 0;
    if (b < NB) {
      start = cnt[b];
      len = cnt[b + 1] - start;
      if (len) {
        int r = b / NNODES;
        bin = (r << 6) + (int)min(len, 63u);
        loc = atomicAdd(&h[bin], 1u);
      }
    }
    __syncthreads();
    unsigned hv = h[tid];
    basearr[tid] = hv ? atomicAdd(&gcur[tid], hv) : 0u;
    __syncthreads();
    if (len) {
      unsigned slot = lbase[bin] + basearr[bin] + loc;
      sstart[slot] = start;
      slen[slot] = len;
      slotof[b] = slot;  // b = r*NNODES + dst: the lookup key k_node needs
    }
  } else {
    int e = (blockIdx.x - 782) * 256 + tid;
    if (e < NEDGES) {
      int r = rel[e]; r = r < 0 ? 0 : (r > NRELS - 1 ? NRELS - 1 : r);
      int key = r * NNODES + dst[e];
      unsigned pos = cnt[key] + atomicAdd(&cur[key], 1u);
      ssrc[pos] = (unsigned)src[e];
    }
  }
}

// ---- group GEMM + per-group max -> plain bf16 stores to gmax ----
// Block = tile; 4 waves split the 128 cols (2 ct each) so B is only 32 VGPRs/wave ->
// 4 waves/SIMD occupancy (was 2: full-width B = 128 VGPRs capped it). All 4 waves
// gather the SAME 16 x-rows per step: wave 0 misses, waves 1-3 hit L1 (4KB/step).
__global__ __launch_bounds__(256, 4) void k_edge(
    const unsigned short* __restrict__ xbf, const unsigned short* __restrict__ Wt,
    const float* __restrict__ bias, const unsigned* __restrict__ ssrc,
    const unsigned* __restrict__ sstart, const unsigned* __restrict__ slen,
    const unsigned* __restrict__ ctrl, unsigned short* __restrict__ gmax) {
  int lane = threadIdx.x & 63;
  int wv = threadIdx.x >> 6;      // wave 0..3 -> col-tiles {2wv, 2wv+1}
  int ct0 = wv * 2;
  int gt1 = (int)ctrl[9], gt2 = (int)ctrl[10], gt3 = (int)ctrl[11];
  int T = (int)ctrl[12];
  int col = lane & 15, quad = lane >> 4;
  bf16x8 B[2][4];
  float bs[2];
  int rcur = -1;

  for (int t = blockIdx.x; t < T; t += gridDim.x) {
    int r = (t >= gt1) + (t >= gt2) + (t >= gt3);
    if (r != rcur) {
      rcur = r;
      const unsigned short* wr = Wt + (r << 14);
#pragma unroll
      for (int i = 0; i < 2; i++) {
#pragma unroll
        for (int kk = 0; kk < 4; kk++)
          B[i][kk] = *(const bf16x8*)(wr + (((ct0 + i) * 16 + col) << 7) + kk * 32 + quad * 8);
        bs[i] = bias[(r << 7) + (ct0 + i) * 16 + col];
      }
    }
    int sbase = t * 16;
    unsigned astart = sstart[sbase + col];   // this lane's A-row group
    int alen = (int)slen[sbase + col];
    int aclamp = alen > 0 ? alen - 1 : 0;
    f32x4 mx[2];
    mx[0] = (f32x4){-3.0e38f, -3.0e38f, -3.0e38f, -3.0e38f};
    mx[1] = mx[0];

    // preload row 0
    unsigned sa = ssrc[astart];  // padding rows: slen=0, sstart=0 -> valid dummy
    const unsigned short* xr = xbf + ((size_t)sa << 7);
    bf16x8 c0 = *(const bf16x8*)(xr + quad * 8);
    bf16x8 c1 = *(const bf16x8*)(xr + 32 + quad * 8);
    bf16x8 c2 = *(const bf16x8*)(xr + 64 + quad * 8);
    bf16x8 c3 = *(const bf16x8*)(xr + 96 + quad * 8);
    int step = 0;
    while (__any(step < alen)) {
      bf16x8 a0 = c0, a1 = c1, a2 = c2, a3 = c3;
      unsigned sa2 = ssrc[astart + min(step + 1, aclamp)];
      const unsigned short* xr2 = xbf + ((size_t)sa2 << 7);
      c0 = *(const bf16x8*)(xr2 + quad * 8);
      c1 = *(const bf16x8*)(xr2 + 32 + quad * 8);
      c2 = *(const bf16x8*)(xr2 + 64 + quad * 8);
      c3 = *(const bf16x8*)(xr2 + 96 + quad * 8);
#pragma unroll
      for (int i = 0; i < 2; i++) {
        f32x4 acc = {0.f, 0.f, 0.f, 0.f};
        acc = __builtin_amdgcn_mfma_f32_16x16x32_bf16(a0, B[i][0], acc, 0, 0, 0);
        acc = __builtin_amdgcn_mfma_f32_16x16x32_bf16(a1, B[i][1], acc, 0, 0, 0);
        acc = __builtin_amdgcn_mfma_f32_16x16x32_bf16(a2, B[i][2], acc, 0, 0, 0);
        acc = __builtin_amdgcn_mfma_f32_16x16x32_bf16(a3, B[i][3], acc, 0, 0, 0);
#pragma unroll
        for (int j = 0; j < 4; j++) mx[i][j] = fmaxf(mx[i][j], acc[j]);
      }
      step++;
    }
#pragma unroll
    for (int i = 0; i < 2; i++) {
#pragma unroll
      for (int j = 0; j < 4; j++) {
        size_t idx = ((size_t)(sbase + quad * 4 + j) << 7) + (unsigned)((ct0 + i) * 16 + col);
        gmax[idx] = f2bf(mx[i][j] + bs[i]);
      }
    }
  }
}

// ---- self-loop GEMM + fused cross-rel max reduce + store f32 ----
// Block = 16-row node group; 4 waves split cols (2 ct each) like k_edge.
__global__ __launch_bounds__(256, 4) void k_node(
    const unsigned short* __restrict__ x, const unsigned short* __restrict__ Wt,
    const float* __restrict__ bias, const unsigned* __restrict__ slotof,
    const unsigned short* __restrict__ gmax, float* __restrict__ out) {
  int lane = threadIdx.x & 63;
  int wv = threadIdx.x >> 6;
  int ct0 = wv * 2;
  int col = lane & 15, quad = lane >> 4;
  int row0 = blockIdx.x * 16;
  if (row0 >= NNODES) return;

  const unsigned short* wr = Wt + (4 << 14);
  bf16x8 B[2][4];
  float bs[2];
#pragma unroll
  for (int i = 0; i < 2; i++) {
#pragma unroll
    for (int kk = 0; kk < 4; kk++)
      B[i][kk] = *(const bf16x8*)(wr + (((ct0 + i) * 16 + col) << 7) + kk * 32 + quad * 8);
    bs[i] = bias[(4 << 7) + (ct0 + i) * 16 + col];
  }
  int na = min(row0 + col, NNODES - 1);
  bf16x8 a0 = *(const bf16x8*)(x + (na << 7) + quad * 8);
  bf16x8 a1 = *(const bf16x8*)(x + (na << 7) + 32 + quad * 8);
  bf16x8 a2 = *(const bf16x8*)(x + (na << 7) + 64 + quad * 8);
  bf16x8 a3 = *(const bf16x8*)(x + (na << 7) + 96 + quad * 8);

  unsigned sl[4][NRELS];
  bool anyv[4];
#pragma unroll
  for (int j = 0; j < 4; j++) {
    int n = row0 + quad * 4 + j;
    bool a = false;
#pragma unroll
    for (int r = 0; r < NRELS; r++) {
      unsigned s = slotof[r * NNODES + n];
      sl[j][r] = s;
      a |= (s != 0xFFFFFFFFu);
    }
    anyv[j] = a;
  }

#pragma unroll
  for (int i = 0; i < 2; i++) {
    f32x4 acc = {0.f, 0.f, 0.f, 0.f};
    acc = __builtin_amdgcn_mfma_f32_16x16x32_bf16(a0, B[i][0], acc, 0, 0, 0);
    acc = __builtin_amdgcn_mfma_f32_16x16x32_bf16(a1, B[i][1], acc, 0, 0, 0);
    acc = __builtin_amdgcn_mfma_f32_16x16x32_bf16(a2, B[i][2], acc, 0, 0, 0);
    acc = __builtin_amdgcn_mfma_f32_16x16x32_bf16(a3, B[i][3], acc, 0, 0, 0);
    int cc = (ct0 + i) * 16 + col;
#pragma unroll
    for (int j = 0; j < 4; j++) {
      int n = row0 + quad * 4 + j;
      if (n < NNODES) {
        float m = -3.0e38f;
#pragma unroll
        for (int r = 0; r < NRELS; r++) {
          unsigned s = sl[j][r];
          if (s != 0xFFFFFFFFu)
            m = fmaxf(m, bf2f(gmax[((size_t)s << 7) + (unsigned)cc]));
        }
        float av = anyv[j] ? m : 0.f;  // DGL zero-fill for nodes w/o in-edges
        out[((size_t)n << 7) + (unsigned)cc] = acc[i == 0 ? j : j] + bs[i] + av;
      }
    }
  }
}

extern "C" void kernel_launch(void* const* d_in, const int* in_sizes, int n_in,
                              void* d_out, int out_size, void* d_ws, size_t ws_size,
                              hipStream_t stream) {
  const float* x = (const float*)d_in[0];
  const float* W = (const float*)d_in[1];
  const float* bias = (const float*)d_in[2];
  const int* src = (const int*)d_in[3];
  const int* dst = (const int*)d_in[4];
  const int* rel = (const int*)d_in[5];

  char* ws = (char*)d_ws;
  unsigned* ssrc = (unsigned*)(ws + SSRC_OFF);
  unsigned* cnt = (unsigned*)(ws + CNT_OFF);
  unsigned* bsum = (unsigned*)(ws + BSUM_OFF);
  unsigned* ctrl = (unsigned*)(ws + CTRL_OFF);
  unsigned* lhist = (unsigned*)(ws + LHIST_OFF);
  unsigned* lbase = (unsigned*)(ws + LBASE_OFF);
  unsigned* gcur = (unsigned*)(ws + GCUR_OFF);
  unsigned* sstart = (unsigned*)(ws + SSTART_OFF);
  unsigned* slen = (unsigned*)(ws + SLEN_OFF);
  unsigned* cur = (unsigned*)(ws + CUR_OFF);
  unsigned* slotof = (unsigned*)(ws + SLOTOF_OFF);
  unsigned short* Wt = (unsigned short*)(ws + WT_OFF);
  unsigned short* xbf = (unsigned short*)(ws + XBF_OFF);
  unsigned short* gmax = (unsigned short*)(ws + GMAX_OFF);

  // zero cnt region so k_prep can fuse the (rel,dst) histogram
  hipMemsetAsync(cnt, 0, BSUM_OFF - CNT_OFF, stream);
  hipLaunchKernelGGL(k_prep, dim3(3133), dim3(256), 0, stream, x, xbf, W, Wt, rel, dst, cnt,
                     bsum, slotof);
  hipLaunchKernelGGL(k_scanA, dim3(NBLKS), dim3(256), 0, stream, cnt, bsum, lhist);
  hipLaunchKernelGGL(k_fix, dim3(NBLKS + 1), dim3(256), 0, stream, cnt, bsum, lhist, lbase,
                     ctrl);
  hipLaunchKernelGGL(k_fill, dim3(782 + 3125), dim3(256), 0, stream, rel, dst, src, cnt, lbase,
                     gcur, sstart, slen, slotof, cur, ssrc);
  hipLaunchKernelGGL(k_edge, dim3(2048), dim3(256), 0, stream, xbf, Wt, bias, ssrc, sstart, slen,
                     ctrl, gmax);
  hipLaunchKernelGGL(k_node, dim3(3125), dim3(256), 0, stream, xbf, Wt, bias, slotof, gmax,
                     (float*)d_out);
}

// Round 10
// 281.104 us; speedup vs baseline: 1.2830x; 1.2830x over previous
//
#include <hip/hip_runtime.h>

// Problem constants (fixed by setup_inputs)
#define NNODES 50000
#define NEDGES 800000
#define DIM    128
#define NRELS  4          // edge relations; weight slice 4 = self-loop
#define NBLK2  25         // scan chunks: 25*2048 = 51200 >= NNODES+1

typedef __attribute__((ext_vector_type(8))) short bf16x8;
typedef __attribute__((ext_vector_type(8))) unsigned short u16x8;
typedef __attribute__((ext_vector_type(4))) float f32x4;

// ---- ws layout (bytes) ----
// Restructured pipeline: dense per-rel transform H[r]=X@W_r+b_r (MFMA, coalesced),
// then dst-sorted segment-max over precomputed H rows (pure BW). No per-rel bins,
// no slot machinery, no gmax.
#define SSRC_OFF 0             // u32[NEDGES]: rowcode = rel*NNODES+src, dst-sorted  3,200,000
#define CNT_OFF  3200000       // u32[51200] dst histogram -> excl scan               204,800
#define BSUM_OFF 3404800       // u32[64]
#define CUR_OFF  3405056       // u32[50048] scatter cursors                          200,192
#define WT_OFF   3605248       // bf16[5*128*128] W^T                                 163,840
#define XBF_OFF  3769088       // bf16[NNODES*DIM]                                 12,800,000
#define H_OFF    16569088      // bf16[4*NNODES*128] per-rel transforms            51,200,000
                               // total ~67.8 MB
#define NZ2      ((WT_OFF - BSUM_OFF) / 4)  // 50,112 u32 zeroed in k_prep

__device__ __forceinline__ unsigned short f2bf(float f) {  // RNE f32->bf16
  unsigned u = __float_as_uint(f);
  return (unsigned short)((u + 0x7FFFu + ((u >> 16) & 1u)) >> 16);
}

// ---- prep: x f32->bf16, W transpose+convert, zero bsum/cur, dst histogram ----
__global__ void k_prep(const float* __restrict__ x, unsigned short* __restrict__ xbf,
                       const float* __restrict__ W, unsigned short* __restrict__ Wt,
                       const int* __restrict__ dst, unsigned* __restrict__ cnt,
                       unsigned* __restrict__ z2) {
  int i = blockIdx.x * blockDim.x + threadIdx.x;
  if (i < NNODES * DIM / 8) {
    const float4* p = (const float4*)x + i * 2;
    float4 v0 = p[0], v1 = p[1];
    u16x8 o;
    o[0] = f2bf(v0.x); o[1] = f2bf(v0.y); o[2] = f2bf(v0.z); o[3] = f2bf(v0.w);
    o[4] = f2bf(v1.x); o[5] = f2bf(v1.y); o[6] = f2bf(v1.z); o[7] = f2bf(v1.w);
    *(u16x8*)(xbf + i * 8) = o;
  }
  if (i < 5 * DIM * DIM) {
    int r = i >> 14, rem = i & 16383, k = rem >> 7, c = rem & 127;
    Wt[(r << 14) + (c << 7) + k] = f2bf(W[i]);
  }
  if (i < NZ2) z2[i] = 0u;
  if (i < NEDGES) atomicAdd(&cnt[dst[i]], 1u);
}

// ---- block-local exclusive scan of 2048-chunks, in place ----
__global__ void k_scanA(unsigned* __restrict__ cnt, unsigned* __restrict__ bsum) {
  __shared__ unsigned sh[256];
  int tid = threadIdx.x;
  int base = blockIdx.x * 2048 + tid * 8;
  unsigned v[8], tsum = 0;
#pragma unroll
  for (int j = 0; j < 8; j++) { v[j] = cnt[base + j]; tsum += v[j]; }
  sh[tid] = tsum;
  __syncthreads();
  for (int off = 1; off < 256; off <<= 1) {
    unsigned t = (tid >= off) ? sh[tid - off] : 0u;
    __syncthreads();
    sh[tid] += t;
    __syncthreads();
  }
  unsigned run = sh[tid] - tsum;
#pragma unroll
  for (int j = 0; j < 8; j++) { unsigned t = v[j]; cnt[base + j] = run; run += t; }
  if (tid == 255) bsum[blockIdx.x] = sh[255];
}

// ---- add block-prefix (<=24 serial adds per block) ----
__global__ void k_fix(unsigned* __restrict__ cnt, const unsigned* __restrict__ bsum) {
  int blk = blockIdx.x;
  if (blk == 0) return;
  unsigned p = 0;
  for (int k = 0; k < blk; k++) p += bsum[k];
  int base = blk * 2048 + threadIdx.x * 8;
#pragma unroll
  for (int j = 0; j < 8; j++) cnt[base + j] += p;
}

// ---- scatter edge rowcodes (rel*NNODES+src) into dst-sorted order ----
__global__ void k_fill(const int* __restrict__ rel, const int* __restrict__ dst,
                       const int* __restrict__ src, const unsigned* __restrict__ cnt,
                       unsigned* __restrict__ cur, unsigned* __restrict__ ssrc) {
  int e = blockIdx.x * blockDim.x + threadIdx.x;
  if (e < NEDGES) {
    int r = rel[e]; r = r < 0 ? 0 : (r > NRELS - 1 ? NRELS - 1 : r);
    int d = dst[e];
    unsigned pos = cnt[d] + atomicAdd(&cur[d], 1u);
    ssrc[pos] = (unsigned)(r * NNODES + src[e]);
  }
}

// ---- dense transform: H[r][n] = xbf[n] @ W_r + b_r (bf16) for r<4;
//      r==4 (self-loop) written as f32 directly into d_out ----
// One wave per 16-row tile; B (W^T) register-resident (8 col-tiles x 4 k) like the
// proven k_node structure; A loads fully coalesced (no gather!).
__global__ __launch_bounds__(256, 2) void k_dense(
    const unsigned short* __restrict__ xbf, const unsigned short* __restrict__ Wt,
    const float* __restrict__ bias, unsigned short* __restrict__ H,
    float* __restrict__ out) {
  int lane = threadIdx.x & 63;
  int wv = threadIdx.x >> 6;
  int tile = blockIdx.x * 4 + wv;           // 5 * 3125 = 15625 tiles
  if (tile >= 5 * (NNODES / 16)) return;
  int r = tile / (NNODES / 16);
  int n0 = (tile % (NNODES / 16)) * 16;
  int col = lane & 15, quad = lane >> 4;

  const unsigned short* wr = Wt + (r << 14);
  bf16x8 B[8][4];
  float bs[8];
#pragma unroll
  for (int ct = 0; ct < 8; ct++) {
#pragma unroll
    for (int kk = 0; kk < 4; kk++)
      B[ct][kk] = *(const bf16x8*)(wr + ((ct * 16 + col) << 7) + kk * 32 + quad * 8);
    bs[ct] = bias[(r << 7) + ct * 16 + col];
  }
  int na = n0 + col;
  bf16x8 a0 = *(const bf16x8*)(xbf + (na << 7) + quad * 8);
  bf16x8 a1 = *(const bf16x8*)(xbf + (na << 7) + 32 + quad * 8);
  bf16x8 a2 = *(const bf16x8*)(xbf + (na << 7) + 64 + quad * 8);
  bf16x8 a3 = *(const bf16x8*)(xbf + (na << 7) + 96 + quad * 8);

#pragma unroll
  for (int ct = 0; ct < 8; ct++) {
    f32x4 acc = {0.f, 0.f, 0.f, 0.f};
    acc = __builtin_amdgcn_mfma_f32_16x16x32_bf16(a0, B[ct][0], acc, 0, 0, 0);
    acc = __builtin_amdgcn_mfma_f32_16x16x32_bf16(a1, B[ct][1], acc, 0, 0, 0);
    acc = __builtin_amdgcn_mfma_f32_16x16x32_bf16(a2, B[ct][2], acc, 0, 0, 0);
    acc = __builtin_amdgcn_mfma_f32_16x16x32_bf16(a3, B[ct][3], acc, 0, 0, 0);
    int cc = ct * 16 + col;
#pragma unroll
    for (int j = 0; j < 4; j++) {
      int n = n0 + quad * 4 + j;
      if (r < NRELS) {
        H[((size_t)(r * NNODES + n) << 7) + (unsigned)cc] = f2bf(acc[j] + bs[ct]);
      } else {
        out[((size_t)n << 7) + (unsigned)cc] = acc[j] + bs[ct];  // self-loop, f32
      }
    }
  }
}

// ---- segment-max over H rows per dst node + combine into d_out (RMW) ----
// One wave per dst group; each lane owns 2 cols (one dword of the bf16 row).
// ~deg independent dword loads in flight per lane -> latency-tolerant, pure BW.
__global__ __launch_bounds__(256, 4) void k_agg(
    const unsigned* __restrict__ cnt, const unsigned* __restrict__ ssrc,
    const unsigned* __restrict__ H32, float* __restrict__ out) {
  int lane = threadIdx.x & 63;
  int wv = threadIdx.x >> 6;
  int n = blockIdx.x * 4 + wv;
  if (n >= NNODES) return;
  unsigned base = cnt[n];
  int deg = (int)(cnt[n + 1] - base);

  float mlo = -3.0e38f, mhi = -3.0e38f;
  int i = 0;
  for (; i + 4 <= deg; i += 4) {
    unsigned c0 = ssrc[base + i], c1 = ssrc[base + i + 1];
    unsigned c2 = ssrc[base + i + 2], c3 = ssrc[base + i + 3];
    unsigned v0 = H32[((size_t)c0 << 6) + lane];
    unsigned v1 = H32[((size_t)c1 << 6) + lane];
    unsigned v2 = H32[((size_t)c2 << 6) + lane];
    unsigned v3 = H32[((size_t)c3 << 6) + lane];
    mlo = fmaxf(mlo, __uint_as_float(v0 << 16));
    mhi = fmaxf(mhi, __uint_as_float(v0 & 0xFFFF0000u));
    mlo = fmaxf(mlo, __uint_as_float(v1 << 16));
    mhi = fmaxf(mhi, __uint_as_float(v1 & 0xFFFF0000u));
    mlo = fmaxf(mlo, __uint_as_float(v2 << 16));
    mhi = fmaxf(mhi, __uint_as_float(v2 & 0xFFFF0000u));
    mlo = fmaxf(mlo, __uint_as_float(v3 << 16));
    mhi = fmaxf(mhi, __uint_as_float(v3 & 0xFFFF0000u));
  }
  for (; i < deg; i++) {
    unsigned c = ssrc[base + i];
    unsigned v = H32[((size_t)c << 6) + lane];
    mlo = fmaxf(mlo, __uint_as_float(v << 16));
    mhi = fmaxf(mhi, __uint_as_float(v & 0xFFFF0000u));
  }
  float2* op = (float2*)out + ((size_t)n << 6) + lane;
  float2 s = *op;                       // self-loop result from k_dense
  if (deg > 0) { s.x += mlo; s.y += mhi; }  // DGL zero-fill: deg==0 adds nothing
  *op = s;
}

extern "C" void kernel_launch(void* const* d_in, const int* in_sizes, int n_in,
                              void* d_out, int out_size, void* d_ws, size_t ws_size,
                              hipStream_t stream) {
  const float* x = (const float*)d_in[0];
  const float* W = (const float*)d_in[1];
  const float* bias = (const float*)d_in[2];
  const int* src = (const int*)d_in[3];
  const int* dst = (const int*)d_in[4];
  const int* rel = (const int*)d_in[5];

  char* ws = (char*)d_ws;
  unsigned* ssrc = (unsigned*)(ws + SSRC_OFF);
  unsigned* cnt = (unsigned*)(ws + CNT_OFF);
  unsigned* bsum = (unsigned*)(ws + BSUM_OFF);
  unsigned* cur = (unsigned*)(ws + CUR_OFF);
  unsigned short* Wt = (unsigned short*)(ws + WT_OFF);
  unsigned short* xbf = (unsigned short*)(ws + XBF_OFF);
  unsigned short* H = (unsigned short*)(ws + H_OFF);
  float* out = (float*)d_out;

  // zero dst-histogram region so k_prep can fuse the histogram
  hipMemsetAsync(cnt, 0, BSUM_OFF - CNT_OFF, stream);
  hipLaunchKernelGGL(k_prep, dim3(3125), dim3(256), 0, stream, x, xbf, W, Wt, dst, cnt, bsum);
  hipLaunchKernelGGL(k_scanA, dim3(NBLK2), dim3(256), 0, stream, cnt, bsum);
  hipLaunchKernelGGL(k_fix, dim3(NBLK2), dim3(256), 0, stream, cnt, bsum);
  hipLaunchKernelGGL(k_fill, dim3(3125), dim3(256), 0, stream, rel, dst, src, cnt, cur, ssrc);
  hipLaunchKernelGGL(k_dense, dim3(3907), dim3(256), 0, stream, xbf, Wt, bias, H, out);
  hipLaunchKernelGGL(k_agg, dim3(12500), dim3(256), 0, stream, cnt, ssrc, (unsigned*)H, out);
}

// Round 11
// 236.626 us; speedup vs baseline: 1.5242x; 1.1880x over previous
//
#include <hip/hip_runtime.h>

// Problem constants (fixed by setup_inputs)
#define NNODES 50000
#define NEDGES 800000
#define DIM    128
#define NRELS  4          // edge relations; weight slice 4 = self-loop
#define NBLK2  25         // scan chunks: 25*2048 = 51200 >= NNODES+1
#define DBLK   128        // k_dense blocks per rel (640 total, 512 waves/rel)

typedef __attribute__((ext_vector_type(8))) short bf16x8;
typedef __attribute__((ext_vector_type(8))) unsigned short u16x8;
typedef __attribute__((ext_vector_type(4))) float f32x4;

// ---- ws layout (bytes) ----
// Pipeline: dense per-rel transform H[r]=X@W_r+b_r (MFMA, coalesced), then
// dst-sorted segment-max over precomputed H rows (pure BW).
#define SSRC_OFF 0             // u32[NEDGES]: rowcode = rel*NNODES+src, dst-sorted  3,200,000
#define CNT_OFF  3200000       // u32[51200] dst histogram -> excl scan               204,800
#define BSUM_OFF 3404800       // u32[64]
#define CUR_OFF  3405056       // u32[50048] scatter cursors                          200,192
#define WT_OFF   3605248       // bf16[5*128*128] W^T                                 163,840
#define XBF_OFF  3769088       // bf16[NNODES*DIM]                                 12,800,000
#define H_OFF    16569088      // bf16[4*NNODES*128] per-rel transforms            51,200,000
                               // total ~67.8 MB
#define NZ2      ((WT_OFF - BSUM_OFF) / 4)  // 50,112 u32 zeroed in k_prep

__device__ __forceinline__ unsigned short f2bf(float f) {  // RNE f32->bf16
  unsigned u = __float_as_uint(f);
  return (unsigned short)((u + 0x7FFFu + ((u >> 16) & 1u)) >> 16);
}

// ---- prep: x f32->bf16, W transpose+convert, zero bsum/cur, dst histogram ----
__global__ void k_prep(const float* __restrict__ x, unsigned short* __restrict__ xbf,
                       const float* __restrict__ W, unsigned short* __restrict__ Wt,
                       const int* __restrict__ dst, unsigned* __restrict__ cnt,
                       unsigned* __restrict__ z2) {
  int i = blockIdx.x * blockDim.x + threadIdx.x;
  if (i < NNODES * DIM / 8) {
    const float4* p = (const float4*)x + i * 2;
    float4 v0 = p[0], v1 = p[1];
    u16x8 o;
    o[0] = f2bf(v0.x); o[1] = f2bf(v0.y); o[2] = f2bf(v0.z); o[3] = f2bf(v0.w);
    o[4] = f2bf(v1.x); o[5] = f2bf(v1.y); o[6] = f2bf(v1.z); o[7] = f2bf(v1.w);
    *(u16x8*)(xbf + i * 8) = o;
  }
  if (i < 5 * DIM * DIM) {
    int r = i >> 14, rem = i & 16383, k = rem >> 7, c = rem & 127;
    Wt[(r << 14) + (c << 7) + k] = f2bf(W[i]);
  }
  if (i < NZ2) z2[i] = 0u;
  if (i < NEDGES) atomicAdd(&cnt[dst[i]], 1u);
}

// ---- block-local exclusive scan of 2048-chunks, in place ----
__global__ void k_scanA(unsigned* __restrict__ cnt, unsigned* __restrict__ bsum) {
  __shared__ unsigned sh[256];
  int tid = threadIdx.x;
  int base = blockIdx.x * 2048 + tid * 8;
  unsigned v[8], tsum = 0;
#pragma unroll
  for (int j = 0; j < 8; j++) { v[j] = cnt[base + j]; tsum += v[j]; }
  sh[tid] = tsum;
  __syncthreads();
  for (int off = 1; off < 256; off <<= 1) {
    unsigned t = (tid >= off) ? sh[tid - off] : 0u;
    __syncthreads();
    sh[tid] += t;
    __syncthreads();
  }
  unsigned run = sh[tid] - tsum;
#pragma unroll
  for (int j = 0; j < 8; j++) { unsigned t = v[j]; cnt[base + j] = run; run += t; }
  if (tid == 255) bsum[blockIdx.x] = sh[255];
}

// ---- add block-prefix (<=24 serial adds per block) ----
__global__ void k_fix(unsigned* __restrict__ cnt, const unsigned* __restrict__ bsum) {
  int blk = blockIdx.x;
  if (blk == 0) return;
  unsigned p = 0;
  for (int k = 0; k < blk; k++) p += bsum[k];
  int base = blk * 2048 + threadIdx.x * 8;
#pragma unroll
  for (int j = 0; j < 8; j++) cnt[base + j] += p;
}

// ---- scatter edge rowcodes (rel*NNODES+src) into dst-sorted order ----
__global__ void k_fill(const int* __restrict__ rel, const int* __restrict__ dst,
                       const int* __restrict__ src, const unsigned* __restrict__ cnt,
                       unsigned* __restrict__ cur, unsigned* __restrict__ ssrc) {
  int e = blockIdx.x * blockDim.x + threadIdx.x;
  if (e < NEDGES) {
    int r = rel[e]; r = r < 0 ? 0 : (r > NRELS - 1 ? NRELS - 1 : r);
    int d = dst[e];
    unsigned pos = cnt[d] + atomicAdd(&cur[d], 1u);
    ssrc[pos] = (unsigned)(r * NNODES + src[e]);
  }
}

// ---- dense transform: H[r][n] = xbf[n] @ W_r + b_r (bf16) for r<4;
//      r==4 (self-loop) written as f32 directly into d_out ----
// Per-rel block regions: B (32 KB W^T) loaded ONCE per wave, then ~6 row-tiles
// looped (round-10 version reloaded B per tile: 500 MB of L2 traffic). H stores
// staged through wave-private LDS -> 4x 1KB contiguous b128 bursts (direct u16
// stores made 32B partial-line writes that RMW-amplified at the memory system).
__global__ __launch_bounds__(256, 2) void k_dense(
    const unsigned short* __restrict__ xbf, const unsigned short* __restrict__ Wt,
    const float* __restrict__ bias, unsigned short* __restrict__ H,
    float* __restrict__ out) {
  __shared__ unsigned short st[4][2048];  // 4 waves x 4 KB tile staging
  int lane = threadIdx.x & 63;
  int wv = threadIdx.x >> 6;
  int r = blockIdx.x / DBLK;              // rel region 0..4
  const int NT = NNODES / 16;             // 3125 row-tiles per rel
  int col = lane & 15, quad = lane >> 4;

  const unsigned short* wr = Wt + (r << 14);
  bf16x8 B[8][4];
  float bs[8];
#pragma unroll
  for (int ct = 0; ct < 8; ct++) {
#pragma unroll
    for (int kk = 0; kk < 4; kk++)
      B[ct][kk] = *(const bf16x8*)(wr + ((ct * 16 + col) << 7) + kk * 32 + quad * 8);
    bs[ct] = bias[(r << 7) + ct * 16 + col];
  }

  for (int t = (blockIdx.x % DBLK) * 4 + wv; t < NT; t += DBLK * 4) {
    int n0 = t * 16;
    int na = n0 + col;
    bf16x8 a0 = *(const bf16x8*)(xbf + (na << 7) + quad * 8);
    bf16x8 a1 = *(const bf16x8*)(xbf + (na << 7) + 32 + quad * 8);
    bf16x8 a2 = *(const bf16x8*)(xbf + (na << 7) + 64 + quad * 8);
    bf16x8 a3 = *(const bf16x8*)(xbf + (na << 7) + 96 + quad * 8);

    if (r < NRELS) {
#pragma unroll
      for (int ct = 0; ct < 8; ct++) {
        f32x4 acc = {0.f, 0.f, 0.f, 0.f};
        acc = __builtin_amdgcn_mfma_f32_16x16x32_bf16(a0, B[ct][0], acc, 0, 0, 0);
        acc = __builtin_amdgcn_mfma_f32_16x16x32_bf16(a1, B[ct][1], acc, 0, 0, 0);
        acc = __builtin_amdgcn_mfma_f32_16x16x32_bf16(a2, B[ct][2], acc, 0, 0, 0);
        acc = __builtin_amdgcn_mfma_f32_16x16x32_bf16(a3, B[ct][3], acc, 0, 0, 0);
        int cc = ct * 16 + col;
#pragma unroll
        for (int j = 0; j < 4; j++) st[wv][(quad * 4 + j) * 128 + cc] = f2bf(acc[j] + bs[ct]);
      }
      // wave-private LDS round-trip (intra-wave lgkmcnt ordering; no __syncthreads)
      unsigned short* gb = H + (((size_t)(r * NNODES + n0)) << 7);
#pragma unroll
      for (int s = 0; s < 4; s++) {
        int off = s * 512 + lane * 8;  // u16 units: 4 bursts of 1KB, 16B/lane
        *(u16x8*)(gb + off) = *(const u16x8*)(&st[wv][off]);
      }
    } else {
#pragma unroll
      for (int ct = 0; ct < 8; ct++) {
        f32x4 acc = {0.f, 0.f, 0.f, 0.f};
        acc = __builtin_amdgcn_mfma_f32_16x16x32_bf16(a0, B[ct][0], acc, 0, 0, 0);
        acc = __builtin_amdgcn_mfma_f32_16x16x32_bf16(a1, B[ct][1], acc, 0, 0, 0);
        acc = __builtin_amdgcn_mfma_f32_16x16x32_bf16(a2, B[ct][2], acc, 0, 0, 0);
        acc = __builtin_amdgcn_mfma_f32_16x16x32_bf16(a3, B[ct][3], acc, 0, 0, 0);
        int cc = ct * 16 + col;
#pragma unroll
        for (int j = 0; j < 4; j++)
          out[((size_t)(n0 + quad * 4 + j) << 7) + (unsigned)cc] = acc[j] + bs[ct];
      }
    }
  }
}

// ---- segment-max over H rows per dst node + combine into d_out (RMW) ----
// One wave per dst group; each lane owns 2 cols (one dword of the bf16 row).
// ~deg independent dword loads in flight per lane -> latency-tolerant, pure BW.
__global__ __launch_bounds__(256, 4) void k_agg(
    const unsigned* __restrict__ cnt, const unsigned* __restrict__ ssrc,
    const unsigned* __restrict__ H32, float* __restrict__ out) {
  int lane = threadIdx.x & 63;
  int wv = threadIdx.x >> 6;
  int n = blockIdx.x * 4 + wv;
  if (n >= NNODES) return;
  unsigned base = cnt[n];
  int deg = (int)(cnt[n + 1] - base);

  float mlo = -3.0e38f, mhi = -3.0e38f;
  int i = 0;
  for (; i + 4 <= deg; i += 4) {
    unsigned c0 = ssrc[base + i], c1 = ssrc[base + i + 1];
    unsigned c2 = ssrc[base + i + 2], c3 = ssrc[base + i + 3];
    unsigned v0 = H32[((size_t)c0 << 6) + lane];
    unsigned v1 = H32[((size_t)c1 << 6) + lane];
    unsigned v2 = H32[((size_t)c2 << 6) + lane];
    unsigned v3 = H32[((size_t)c3 << 6) + lane];
    mlo = fmaxf(mlo, __uint_as_float(v0 << 16));
    mhi = fmaxf(mhi, __uint_as_float(v0 & 0xFFFF0000u));
    mlo = fmaxf(mlo, __uint_as_float(v1 << 16));
    mhi = fmaxf(mhi, __uint_as_float(v1 & 0xFFFF0000u));
    mlo = fmaxf(mlo, __uint_as_float(v2 << 16));
    mhi = fmaxf(mhi, __uint_as_float(v2 & 0xFFFF0000u));
    mlo = fmaxf(mlo, __uint_as_float(v3 << 16));
    mhi = fmaxf(mhi, __uint_as_float(v3 & 0xFFFF0000u));
  }
  for (; i < deg; i++) {
    unsigned c = ssrc[base + i];
    unsigned v = H32[((size_t)c << 6) + lane];
    mlo = fmaxf(mlo, __uint_as_float(v << 16));
    mhi = fmaxf(mhi, __uint_as_float(v & 0xFFFF0000u));
  }
  float2* op = (float2*)out + ((size_t)n << 6) + lane;
  float2 s = *op;                       // self-loop result from k_dense
  if (deg > 0) { s.x += mlo; s.y += mhi; }  // DGL zero-fill: deg==0 adds nothing
  *op = s;
}

extern "C" void kernel_launch(void* const* d_in, const int* in_sizes, int n_in,
                              void* d_out, int out_size, void* d_ws, size_t ws_size,
                              hipStream_t stream) {
  const float* x = (const float*)d_in[0];
  const float* W = (const float*)d_in[1];
  const float* bias = (const float*)d_in[2];
  const int* src = (const int*)d_in[3];
  const int* dst = (const int*)d_in[4];
  const int* rel = (const int*)d_in[5];

  char* ws = (char*)d_ws;
  unsigned* ssrc = (unsigned*)(ws + SSRC_OFF);
  unsigned* cnt = (unsigned*)(ws + CNT_OFF);
  unsigned* bsum = (unsigned*)(ws + BSUM_OFF);
  unsigned* cur = (unsigned*)(ws + CUR_OFF);
  unsigned short* Wt = (unsigned short*)(ws + WT_OFF);
  unsigned short* xbf = (unsigned short*)(ws + XBF_OFF);
  unsigned short* H = (unsigned short*)(ws + H_OFF);
  float* out = (float*)d_out;

  // zero dst-histogram region so k_prep can fuse the histogram
  hipMemsetAsync(cnt, 0, BSUM_OFF - CNT_OFF, stream);
  hipLaunchKernelGGL(k_prep, dim3(3125), dim3(256), 0, stream, x, xbf, W, Wt, dst, cnt, bsum);
  hipLaunchKernelGGL(k_scanA, dim3(NBLK2), dim3(256), 0, stream, cnt, bsum);
  hipLaunchKernelGGL(k_fix, dim3(NBLK2), dim3(256), 0, stream, cnt, bsum);
  hipLaunchKernelGGL(k_fill, dim3(3125), dim3(256), 0, stream, rel, dst, src, cnt, cur, ssrc);
  hipLaunchKernelGGL(k_dense, dim3(5 * DBLK), dim3(256), 0, stream, xbf, Wt, bias, H, out);
  hipLaunchKernelGGL(k_agg, dim3(12500), dim3(256), 0, stream, cnt, ssrc, (unsigned*)H, out);
}

// Round 12
// 230.923 us; speedup vs baseline: 1.5618x; 1.0247x over previous
//
#include <hip/hip_runtime.h>

// Problem constants (fixed by setup_inputs)
#define NNODES 50000
#define NEDGES 800000
#define DIM    128
#define NRELS  4          // edge relations; weight slice 4 = self-loop
#define NBLK2  25         // scan chunks: 25*2048 = 51200 >= NNODES+1
#define DBLK   128        // k_dfill dense blocks per rel (640 total)
#define NDB    (5*DBLK)   // 640 dense blocks
#define NFB    3125       // fill blocks

typedef __attribute__((ext_vector_type(8))) short bf16x8;
typedef __attribute__((ext_vector_type(8))) unsigned short u16x8;
typedef __attribute__((ext_vector_type(4))) float f32x4;

// ---- ws layout (bytes) ----
#define SSRC_OFF 0             // u32[NEDGES]: rowcode = rel*NNODES+src, dst-sorted  3,200,000
#define CNT_OFF  3200000       // u32[51200] dst histogram -> excl scan               204,800
#define BSUM_OFF 3404800       // u32[64]
#define CUR_OFF  3405056       // u32[50048] scatter cursors                          200,192
#define WT_OFF   3605248       // bf16[5*128*128] W^T                                 163,840
#define XBF_OFF  3769088       // bf16[NNODES*DIM]                                 12,800,000
#define H_OFF    16569088      // bf16[4*NNODES*128] per-rel transforms            51,200,000
                               // total ~67.8 MB
#define NZ2      ((WT_OFF - BSUM_OFF) / 4)  // 50,112 u32 zeroed in k_prep

__device__ __forceinline__ unsigned short f2bf(float f) {  // RNE f32->bf16
  unsigned u = __float_as_uint(f);
  return (unsigned short)((u + 0x7FFFu + ((u >> 16) & 1u)) >> 16);
}

// ---- prep: x f32->bf16, W transpose+convert, zero bsum/cur, dst histogram ----
__global__ void k_prep(const float* __restrict__ x, unsigned short* __restrict__ xbf,
                       const float* __restrict__ W, unsigned short* __restrict__ Wt,
                       const int* __restrict__ dst, unsigned* __restrict__ cnt,
                       unsigned* __restrict__ z2) {
  int i = blockIdx.x * blockDim.x + threadIdx.x;
  if (i < NNODES * DIM / 8) {
    const float4* p = (const float4*)x + i * 2;
    float4 v0 = p[0], v1 = p[1];
    u16x8 o;
    o[0] = f2bf(v0.x); o[1] = f2bf(v0.y); o[2] = f2bf(v0.z); o[3] = f2bf(v0.w);
    o[4] = f2bf(v1.x); o[5] = f2bf(v1.y); o[6] = f2bf(v1.z); o[7] = f2bf(v1.w);
    *(u16x8*)(xbf + i * 8) = o;
  }
  if (i < 5 * DIM * DIM) {
    int r = i >> 14, rem = i & 16383, k = rem >> 7, c = rem & 127;
    Wt[(r << 14) + (c << 7) + k] = f2bf(W[i]);
  }
  if (i < NZ2) z2[i] = 0u;
  if (i < NEDGES) atomicAdd(&cnt[dst[i]], 1u);
}

// ---- block-local exclusive scan of 2048-chunks, in place ----
__global__ void k_scanA(unsigned* __restrict__ cnt, unsigned* __restrict__ bsum) {
  __shared__ unsigned sh[256];
  int tid = threadIdx.x;
  int base = blockIdx.x * 2048 + tid * 8;
  unsigned v[8], tsum = 0;
#pragma unroll
  for (int j = 0; j < 8; j++) { v[j] = cnt[base + j]; tsum += v[j]; }
  sh[tid] = tsum;
  __syncthreads();
  for (int off = 1; off < 256; off <<= 1) {
    unsigned t = (tid >= off) ? sh[tid - off] : 0u;
    __syncthreads();
    sh[tid] += t;
    __syncthreads();
  }
  unsigned run = sh[tid] - tsum;
#pragma unroll
  for (int j = 0; j < 8; j++) { unsigned t = v[j]; cnt[base + j] = run; run += t; }
  if (tid == 255) bsum[blockIdx.x] = sh[255];
}

// ---- add block-prefix (<=24 serial adds per block) ----
__global__ void k_fix(unsigned* __restrict__ cnt, const unsigned* __restrict__ bsum) {
  int blk = blockIdx.x;
  if (blk == 0) return;
  unsigned p = 0;
  for (int k = 0; k < blk; k++) p += bsum[k];
  int base = blk * 2048 + threadIdx.x * 8;
#pragma unroll
  for (int j = 0; j < 8; j++) cnt[base + j] += p;
}

// ---- FUSED dense + fill: disjoint block ranges overlap the MFMA/store-bound dense
// transform with the latency/partial-line-bound edge scatter (k_dense was serialized
// after k_fill in r11 despite being independent of the sort chain; m114: separate
// waves co-schedule on different pipes).
// Blocks [0,NDB): H[r][n]=xbf[n]@W_r+b_r (bf16, LDS-staged stores); r==4 -> f32 d_out.
// Blocks [NDB,NDB+NFB): scatter edge rowcodes into dst-sorted ssrc.
__global__ __launch_bounds__(256, 2) void k_dfill(
    const unsigned short* __restrict__ xbf, const unsigned short* __restrict__ Wt,
    const float* __restrict__ bias, unsigned short* __restrict__ H,
    float* __restrict__ out, const int* __restrict__ rel, const int* __restrict__ dst,
    const int* __restrict__ src, const unsigned* __restrict__ cnt,
    unsigned* __restrict__ cur, unsigned* __restrict__ ssrc) {
  if (blockIdx.x >= NDB) {
    // ---- fill part ----
    int e = (blockIdx.x - NDB) * 256 + threadIdx.x;
    if (e < NEDGES) {
      int r = rel[e]; r = r < 0 ? 0 : (r > NRELS - 1 ? NRELS - 1 : r);
      int d = dst[e];
      unsigned pos = cnt[d] + atomicAdd(&cur[d], 1u);
      ssrc[pos] = (unsigned)(r * NNODES + src[e]);
    }
    return;
  }
  // ---- dense part ----
  __shared__ unsigned short st[4][2048];  // 4 waves x 4 KB tile staging
  int lane = threadIdx.x & 63;
  int wv = threadIdx.x >> 6;
  int r = blockIdx.x / DBLK;              // rel region 0..4
  const int NT = NNODES / 16;             // 3125 row-tiles per rel
  int col = lane & 15, quad = lane >> 4;

  const unsigned short* wr = Wt + (r << 14);
  bf16x8 B[8][4];
  float bs[8];
#pragma unroll
  for (int ct = 0; ct < 8; ct++) {
#pragma unroll
    for (int kk = 0; kk < 4; kk++)
      B[ct][kk] = *(const bf16x8*)(wr + ((ct * 16 + col) << 7) + kk * 32 + quad * 8);
    bs[ct] = bias[(r << 7) + ct * 16 + col];
  }

  for (int t = (blockIdx.x % DBLK) * 4 + wv; t < NT; t += DBLK * 4) {
    int n0 = t * 16;
    int na = n0 + col;
    bf16x8 a0 = *(const bf16x8*)(xbf + (na << 7) + quad * 8);
    bf16x8 a1 = *(const bf16x8*)(xbf + (na << 7) + 32 + quad * 8);
    bf16x8 a2 = *(const bf16x8*)(xbf + (na << 7) + 64 + quad * 8);
    bf16x8 a3 = *(const bf16x8*)(xbf + (na << 7) + 96 + quad * 8);

    if (r < NRELS) {
#pragma unroll
      for (int ct = 0; ct < 8; ct++) {
        f32x4 acc = {0.f, 0.f, 0.f, 0.f};
        acc = __builtin_amdgcn_mfma_f32_16x16x32_bf16(a0, B[ct][0], acc, 0, 0, 0);
        acc = __builtin_amdgcn_mfma_f32_16x16x32_bf16(a1, B[ct][1], acc, 0, 0, 0);
        acc = __builtin_amdgcn_mfma_f32_16x16x32_bf16(a2, B[ct][2], acc, 0, 0, 0);
        acc = __builtin_amdgcn_mfma_f32_16x16x32_bf16(a3, B[ct][3], acc, 0, 0, 0);
        int cc = ct * 16 + col;
#pragma unroll
        for (int j = 0; j < 4; j++) st[wv][(quad * 4 + j) * 128 + cc] = f2bf(acc[j] + bs[ct]);
      }
      // wave-private LDS round-trip (intra-wave lgkmcnt ordering; no __syncthreads)
      unsigned short* gb = H + (((size_t)(r * NNODES + n0)) << 7);
#pragma unroll
      for (int s = 0; s < 4; s++) {
        int off = s * 512 + lane * 8;  // u16 units: 4 bursts of 1KB, 16B/lane
        *(u16x8*)(gb + off) = *(const u16x8*)(&st[wv][off]);
      }
    } else {
#pragma unroll
      for (int ct = 0; ct < 8; ct++) {
        f32x4 acc = {0.f, 0.f, 0.f, 0.f};
        acc = __builtin_amdgcn_mfma_f32_16x16x32_bf16(a0, B[ct][0], acc, 0, 0, 0);
        acc = __builtin_amdgcn_mfma_f32_16x16x32_bf16(a1, B[ct][1], acc, 0, 0, 0);
        acc = __builtin_amdgcn_mfma_f32_16x16x32_bf16(a2, B[ct][2], acc, 0, 0, 0);
        acc = __builtin_amdgcn_mfma_f32_16x16x32_bf16(a3, B[ct][3], acc, 0, 0, 0);
        int cc = ct * 16 + col;
#pragma unroll
        for (int j = 0; j < 4; j++)
          out[((size_t)(n0 + quad * 4 + j) << 7) + (unsigned)cc] = acc[j] + bs[ct];
      }
    }
  }
}

// ---- segment-max over H rows per dst node + combine into d_out (RMW) ----
// One wave per dst group; each lane owns 2 cols (one dword of the bf16 row).
__global__ __launch_bounds__(256, 4) void k_agg(
    const unsigned* __restrict__ cnt, const unsigned* __restrict__ ssrc,
    const unsigned* __restrict__ H32, float* __restrict__ out) {
  int lane = threadIdx.x & 63;
  int wv = threadIdx.x >> 6;
  int n = blockIdx.x * 4 + wv;
  if (n >= NNODES) return;
  unsigned base = cnt[n];
  int deg = (int)(cnt[n + 1] - base);

  float mlo = -3.0e38f, mhi = -3.0e38f;
  int i = 0;
  for (; i + 4 <= deg; i += 4) {
    unsigned c0 = ssrc[base + i], c1 = ssrc[base + i + 1];
    unsigned c2 = ssrc[base + i + 2], c3 = ssrc[base + i + 3];
    unsigned v0 = H32[((size_t)c0 << 6) + lane];
    unsigned v1 = H32[((size_t)c1 << 6) + lane];
    unsigned v2 = H32[((size_t)c2 << 6) + lane];
    unsigned v3 = H32[((size_t)c3 << 6) + lane];
    mlo = fmaxf(mlo, __uint_as_float(v0 << 16));
    mhi = fmaxf(mhi, __uint_as_float(v0 & 0xFFFF0000u));
    mlo = fmaxf(mlo, __uint_as_float(v1 << 16));
    mhi = fmaxf(mhi, __uint_as_float(v1 & 0xFFFF0000u));
    mlo = fmaxf(mlo, __uint_as_float(v2 << 16));
    mhi = fmaxf(mhi, __uint_as_float(v2 & 0xFFFF0000u));
    mlo = fmaxf(mlo, __uint_as_float(v3 << 16));
    mhi = fmaxf(mhi, __uint_as_float(v3 & 0xFFFF0000u));
  }
  for (; i < deg; i++) {
    unsigned c = ssrc[base + i];
    unsigned v = H32[((size_t)c << 6) + lane];
    mlo = fmaxf(mlo, __uint_as_float(v << 16));
    mhi = fmaxf(mhi, __uint_as_float(v & 0xFFFF0000u));
  }
  float2* op = (float2*)out + ((size_t)n << 6) + lane;
  float2 s = *op;                       // self-loop result from k_dfill
  if (deg > 0) { s.x += mlo; s.y += mhi; }  // DGL zero-fill: deg==0 adds nothing
  *op = s;
}

extern "C" void kernel_launch(void* const* d_in, const int* in_sizes, int n_in,
                              void* d_out, int out_size, void* d_ws, size_t ws_size,
                              hipStream_t stream) {
  const float* x = (const float*)d_in[0];
  const float* W = (const float*)d_in[1];
  const float* bias = (const float*)d_in[2];
  const int* src = (const int*)d_in[3];
  const int* dst = (const int*)d_in[4];
  const int* rel = (const int*)d_in[5];

  char* ws = (char*)d_ws;
  unsigned* ssrc = (unsigned*)(ws + SSRC_OFF);
  unsigned* cnt = (unsigned*)(ws + CNT_OFF);
  unsigned* bsum = (unsigned*)(ws + BSUM_OFF);
  unsigned* cur = (unsigned*)(ws + CUR_OFF);
  unsigned short* Wt = (unsigned short*)(ws + WT_OFF);
  unsigned short* xbf = (unsigned short*)(ws + XBF_OFF);
  unsigned short* H = (unsigned short*)(ws + H_OFF);
  float* out = (float*)d_out;

  // zero dst-histogram region so k_prep can fuse the histogram
  hipMemsetAsync(cnt, 0, BSUM_OFF - CNT_OFF, stream);
  hipLaunchKernelGGL(k_prep, dim3(3125), dim3(256), 0, stream, x, xbf, W, Wt, dst, cnt, bsum);
  hipLaunchKernelGGL(k_scanA, dim3(NBLK2), dim3(256), 0, stream, cnt, bsum);
  hipLaunchKernelGGL(k_fix, dim3(NBLK2), dim3(256), 0, stream, cnt, bsum);
  hipLaunchKernelGGL(k_dfill, dim3(NDB + NFB), dim3(256), 0, stream, xbf, Wt, bias, H, out, rel,
                     dst, src, cnt, cur, ssrc);
  hipLaunchKernelGGL(k_agg, dim3(12500), dim3(256), 0, stream, cnt, ssrc, (unsigned*)H, out);
}